// Round 3
// baseline (30.790 us; speedup 1.0000x reference)
//
#include <hip/hip_runtime.h>
#include <math.h>

typedef float f32x4 __attribute__((ext_vector_type(4)));

// out[bn, y, x] = (valid && y in [sy1,sy2) && x in [sx1,sx2) ? feat[rowS(y)] : 0)
//              + (valid && y in [oy1,oy2) && x in [ox1,ox2) ? feat[rowO(y)] : 0)
// rowS(y) = clip((y - sy1) * C / sh, 0, C-1), nearest-neighbor 1-D interp.
//
// Write-BW-bound: 134 MB out. Strategy: per-row values staged in LDS (one
// int-div per row), then a pure streaming-store phase with nontemporal
// float4 stores and division-free incremental indexing.
__global__ void rs_rel_spatial_kernel(const float* __restrict__ rel,
                                      const int* __restrict__ bbox,
                                      float* __restrict__ out,
                                      int C, int w) {
    const int bn = blockIdx.x;
    extern __shared__ float smem[];
    float* sval = smem;      // [w] subject-box per-row value (0 if masked)
    float* oval = smem + w;  // [w] object-box per-row value

    const int* bb = bbox + (size_t)bn * 8;
    const int sx1 = bb[0] >> 1, sy1 = bb[1] >> 1, sx2 = bb[2] >> 1, sy2 = bb[3] >> 1;
    const int ox1 = bb[4] >> 1, oy1 = bb[5] >> 1, ox2 = bb[6] >> 1, oy2 = bb[7] >> 1;
    const int sh = sy2 - sy1, sw_ = sx2 - sx1;
    const int oh = oy2 - oy1, ow_ = ox2 - ox1;
    const bool valid = (sh >= 5) & (sw_ >= 5) & (oh >= 5) & (ow_ >= 5);

    const float* feat = rel + (size_t)bn * C;

    // Phase 1: per-row gathered values into LDS
    for (int r = threadIdx.x; r < 2 * w; r += blockDim.x) {
        float v = 0.f;
        if (r < w) {
            const int y = r;
            if (valid && y >= sy1 && y < sy2) {
                int row = (y - sy1) * C / sh;       // sh >= 5 when valid
                if (row > C - 1) row = C - 1;
                v = feat[row];
            }
            sval[y] = v;
        } else {
            const int y = r - w;
            if (valid && y >= oy1 && y < oy2) {
                int row = (y - oy1) * C / oh;
                if (row > C - 1) row = C - 1;
                v = feat[row];
            }
            oval[y] = v;
        }
    }
    __syncthreads();

    float* obase = out + (size_t)bn * w * w;

    const int qpr = w >> 2;  // float4 quads per row
    if ((w & 3) == 0 && qpr > 0 && (blockDim.x % qpr) == 0) {
        // Division-free streaming phase: thread t owns quad column (t % qpr)
        // of rows t/qpr, t/qpr + rstep, ...  Store ptr just increments.
        const int t     = threadIdx.x;
        int y           = t / qpr;                 // one div, pre-loop
        const int x0    = (t - y * qpr) << 2;
        const int rstep = blockDim.x / qpr;
        f32x4* pout     = reinterpret_cast<f32x4*>(obase) + t;
        const int pstep = blockDim.x;

        for (; y < w; y += rstep, pout += pstep) {
            const float sv = sval[y];
            const float ov = oval[y];
            f32x4 res;
#pragma unroll
            for (int j = 0; j < 4; ++j) {
                const int x = x0 + j;
                float acc = 0.f;
                if (x >= sx1 && x < sx2) acc += sv;
                if (x >= ox1 && x < ox2) acc += ov;
                res[j] = acc;
            }
            __builtin_nontemporal_store(res, pout);
        }
    } else {
        // Scalar fallback for odd shapes
        const int total = w * w;
        for (int i = threadIdx.x; i < total; i += blockDim.x) {
            const int y = i / w;
            const int x = i - y * w;
            float acc = 0.f;
            if (x >= sx1 && x < sx2) acc += sval[y];
            if (x >= ox1 && x < ox2) acc += oval[y];
            obase[i] = acc;
        }
    }
}

extern "C" void kernel_launch(void* const* d_in, const int* in_sizes, int n_in,
                              void* d_out, int out_size, void* d_ws, size_t ws_size,
                              hipStream_t stream) {
    const float* rel  = (const float*)d_in[0];
    const int*   bbox = (const int*)d_in[1];
    float*       out  = (float*)d_out;

    // Shapes from flat sizes: bbox is [B,N,8] -> BN; rel is [BN,C]; out is [BN,w,w]
    const int BN = in_sizes[1] / 8;
    const int C  = in_sizes[0] / BN;
    const int w  = (int)(sqrt((double)(out_size / BN)) + 0.5);

    dim3 grid(BN);
    dim3 block(256);
    const size_t shmem = (size_t)2 * w * sizeof(float);
    hipLaunchKernelGGL(rs_rel_spatial_kernel, grid, block, shmem, stream,
                       rel, bbox, out, C, w);
}

// Round 4
// 24.792 us; speedup vs baseline: 1.2419x; 1.2419x over previous
//
#include <hip/hip_runtime.h>
#include <math.h>

// out[bn, y, x] = (valid && y in [sy1,sy2) && x in [sx1,sx2) ? feat[rowS(y)] : 0)
//              + (valid && y in [oy1,oy2) && x in [ox1,ox2) ? feat[rowO(y)] : 0)
// rowS(y) = clip((y - sy1) * C / sh, 0, C-1), nearest-neighbor 1-D interp.
//
// Write-BW-bound: 134 MB out. Per-row values staged in LDS (one int-div per
// row), then a pure streaming-store phase with plain float4 stores (NT stores
// measured 28% SLOWER on gfx950 — they bypass L2 write-combining) and
// division-free incremental indexing.
__global__ void rs_rel_spatial_kernel(const float* __restrict__ rel,
                                      const int* __restrict__ bbox,
                                      float* __restrict__ out,
                                      int C, int w) {
    const int bn = blockIdx.x;
    extern __shared__ float smem[];
    float* sval = smem;      // [w] subject-box per-row value (0 if masked)
    float* oval = smem + w;  // [w] object-box per-row value

    const int* bb = bbox + (size_t)bn * 8;
    const int sx1 = bb[0] >> 1, sy1 = bb[1] >> 1, sx2 = bb[2] >> 1, sy2 = bb[3] >> 1;
    const int ox1 = bb[4] >> 1, oy1 = bb[5] >> 1, ox2 = bb[6] >> 1, oy2 = bb[7] >> 1;
    const int sh = sy2 - sy1, sw_ = sx2 - sx1;
    const int oh = oy2 - oy1, ow_ = ox2 - ox1;
    const bool valid = (sh >= 5) & (sw_ >= 5) & (oh >= 5) & (ow_ >= 5);

    const float* feat = rel + (size_t)bn * C;

    // Phase 1: per-row gathered values into LDS
    for (int r = threadIdx.x; r < 2 * w; r += blockDim.x) {
        float v = 0.f;
        if (r < w) {
            const int y = r;
            if (valid && y >= sy1 && y < sy2) {
                int row = (y - sy1) * C / sh;       // sh >= 5 when valid
                if (row > C - 1) row = C - 1;
                v = feat[row];
            }
            sval[y] = v;
        } else {
            const int y = r - w;
            if (valid && y >= oy1 && y < oy2) {
                int row = (y - oy1) * C / oh;
                if (row > C - 1) row = C - 1;
                v = feat[row];
            }
            oval[y] = v;
        }
    }
    __syncthreads();

    float* obase = out + (size_t)bn * w * w;

    const int qpr = w >> 2;  // float4 quads per row
    if ((w & 3) == 0 && qpr > 0 && (blockDim.x % qpr) == 0) {
        // Division-free streaming phase: thread t owns quad column (t % qpr)
        // of rows t/qpr, t/qpr + rstep, ...  Store ptr just increments.
        const int t     = threadIdx.x;
        int y           = t / qpr;                 // one div, pre-loop
        const int x0    = (t - y * qpr) << 2;
        const int rstep = blockDim.x / qpr;
        float4* pout    = reinterpret_cast<float4*>(obase) + t;
        const int pstep = blockDim.x;

        for (; y < w; y += rstep, pout += pstep) {
            const float sv = sval[y];
            const float ov = oval[y];
            float4 res;
            float* rp = &res.x;
#pragma unroll
            for (int j = 0; j < 4; ++j) {
                const int x = x0 + j;
                float acc = 0.f;
                if (x >= sx1 && x < sx2) acc += sv;
                if (x >= ox1 && x < ox2) acc += ov;
                rp[j] = acc;
            }
            *pout = res;
        }
    } else {
        // Scalar fallback for odd shapes
        const int total = w * w;
        for (int i = threadIdx.x; i < total; i += blockDim.x) {
            const int y = i / w;
            const int x = i - y * w;
            float acc = 0.f;
            if (x >= sx1 && x < sx2) acc += sval[y];
            if (x >= ox1 && x < ox2) acc += oval[y];
            obase[i] = acc;
        }
    }
}

extern "C" void kernel_launch(void* const* d_in, const int* in_sizes, int n_in,
                              void* d_out, int out_size, void* d_ws, size_t ws_size,
                              hipStream_t stream) {
    const float* rel  = (const float*)d_in[0];
    const int*   bbox = (const int*)d_in[1];
    float*       out  = (float*)d_out;

    // Shapes from flat sizes: bbox is [B,N,8] -> BN; rel is [BN,C]; out is [BN,w,w]
    const int BN = in_sizes[1] / 8;
    const int C  = in_sizes[0] / BN;
    const int w  = (int)(sqrt((double)(out_size / BN)) + 0.5);

    dim3 grid(BN);
    dim3 block(256);
    const size_t shmem = (size_t)2 * w * sizeof(float);
    hipLaunchKernelGGL(rs_rel_spatial_kernel, grid, block, shmem, stream,
                       rel, bbox, out, C, w);
}

// Round 5
// 24.478 us; speedup vs baseline: 1.2578x; 1.0128x over previous
//
#include <hip/hip_runtime.h>
#include <math.h>

// out[bn, y, x] = (valid && y in [sy1,sy2) && x in [sx1,sx2) ? feat[rowS(y)] : 0)
//              + (valid && y in [oy1,oy2) && x in [ox1,ox2) ? feat[rowO(y)] : 0)
// rowS(y) = clip((y - sy1) * C / sh, 0, C-1), nearest-neighbor 1-D interp.
//
// Write-BW-bound: 134 MB out. Phase 1 stages per-row values in LDS (one
// int-div per row). Phase 2 (specialized w=128/block=256): preload all 16
// row values into registers, hoist the loop-invariant x-masks, then emit 16
// back-to-back float4 stores with no memory reads between them (fill-like
// store stream). NT stores measured 28% SLOWER on gfx950 (bypass L2 write
// combining) — plain stores only.
__global__ void rs_rel_spatial_kernel(const float* __restrict__ rel,
                                      const int* __restrict__ bbox,
                                      float* __restrict__ out,
                                      int C, int w) {
    const int bn = blockIdx.x;
    extern __shared__ float smem[];
    float* sval = smem;      // [w] subject-box per-row value (0 if masked)
    float* oval = smem + w;  // [w] object-box per-row value

    const int* bb = bbox + (size_t)bn * 8;
    const int sx1 = bb[0] >> 1, sy1 = bb[1] >> 1, sx2 = bb[2] >> 1, sy2 = bb[3] >> 1;
    const int ox1 = bb[4] >> 1, oy1 = bb[5] >> 1, ox2 = bb[6] >> 1, oy2 = bb[7] >> 1;
    const int sh = sy2 - sy1, sw_ = sx2 - sx1;
    const int oh = oy2 - oy1, ow_ = ox2 - ox1;
    const bool valid = (sh >= 5) & (sw_ >= 5) & (oh >= 5) & (ow_ >= 5);

    const float* feat = rel + (size_t)bn * C;

    // Phase 1: per-row gathered values into LDS
    for (int r = threadIdx.x; r < 2 * w; r += blockDim.x) {
        float v = 0.f;
        if (r < w) {
            const int y = r;
            if (valid && y >= sy1 && y < sy2) {
                int row = (y - sy1) * C / sh;       // sh >= 5 when valid
                if (row > C - 1) row = C - 1;
                v = feat[row];
            }
            sval[y] = v;
        } else {
            const int y = r - w;
            if (valid && y >= oy1 && y < oy2) {
                int row = (y - oy1) * C / oh;
                if (row > C - 1) row = C - 1;
                v = feat[row];
            }
            oval[y] = v;
        }
    }
    __syncthreads();

    float* obase = out + (size_t)bn * w * w;

    if (w == 128 && blockDim.x == 256) {
        // Specialized: qpr=32 quads/row, rstep=8, 16 iterations, all static.
        const int t  = threadIdx.x;
        const int y0 = t >> 5;            // first row this thread touches
        const int x0 = (t & 31) << 2;     // quad's x base

        // Loop-invariant x-masks (x never changes across iterations).
        bool ms[4], mo[4];
#pragma unroll
        for (int j = 0; j < 4; ++j) {
            const int x = x0 + j;
            ms[j] = (x >= sx1) & (x < sx2);
            mo[j] = (x >= ox1) & (x < ox2);
        }

        // Preload all 16 rows' values into registers (static indices).
        float svr[16], ovr[16];
#pragma unroll
        for (int k = 0; k < 16; ++k) {
            const int y = y0 + (k << 3);
            svr[k] = sval[y];
            ovr[k] = oval[y];
        }

        // Pure store stream: 16 float4 stores, no memory reads in between.
        float4* pout = reinterpret_cast<float4*>(obase) + t;
#pragma unroll
        for (int k = 0; k < 16; ++k, pout += 256) {
            float4 res;
            float* rp = &res.x;
#pragma unroll
            for (int j = 0; j < 4; ++j) {
                float acc = ms[j] ? svr[k] : 0.f;
                if (mo[j]) acc += ovr[k];
                rp[j] = acc;
            }
            *pout = res;
        }
    } else if ((w & 3) == 0 && (w >> 2) > 0 && (blockDim.x % (w >> 2)) == 0) {
        // Generic vectorized fallback
        const int qpr   = w >> 2;
        const int t     = threadIdx.x;
        int y           = t / qpr;
        const int x0    = (t - y * qpr) << 2;
        const int rstep = blockDim.x / qpr;
        float4* pout    = reinterpret_cast<float4*>(obase) + t;
        const int pstep = blockDim.x;

        for (; y < w; y += rstep, pout += pstep) {
            const float sv = sval[y];
            const float ov = oval[y];
            float4 res;
            float* rp = &res.x;
#pragma unroll
            for (int j = 0; j < 4; ++j) {
                const int x = x0 + j;
                float acc = 0.f;
                if (x >= sx1 && x < sx2) acc += sv;
                if (x >= ox1 && x < ox2) acc += ov;
                rp[j] = acc;
            }
            *pout = res;
        }
    } else {
        // Scalar fallback for odd shapes
        const int total = w * w;
        for (int i = threadIdx.x; i < total; i += blockDim.x) {
            const int y = i / w;
            const int x = i - y * w;
            float acc = 0.f;
            if (x >= sx1 && x < sx2) acc += sval[y];
            if (x >= ox1 && x < ox2) acc += oval[y];
            obase[i] = acc;
        }
    }
}

extern "C" void kernel_launch(void* const* d_in, const int* in_sizes, int n_in,
                              void* d_out, int out_size, void* d_ws, size_t ws_size,
                              hipStream_t stream) {
    const float* rel  = (const float*)d_in[0];
    const int*   bbox = (const int*)d_in[1];
    float*       out  = (float*)d_out;

    // Shapes from flat sizes: bbox is [B,N,8] -> BN; rel is [BN,C]; out is [BN,w,w]
    const int BN = in_sizes[1] / 8;
    const int C  = in_sizes[0] / BN;
    const int w  = (int)(sqrt((double)(out_size / BN)) + 0.5);

    dim3 grid(BN);
    dim3 block(256);
    const size_t shmem = (size_t)2 * w * sizeof(float);
    hipLaunchKernelGGL(rs_rel_spatial_kernel, grid, block, shmem, stream,
                       rel, bbox, out, C, w);
}